// Round 4
// baseline (506.647 us; speedup 1.0000x reference)
//
#include <hip/hip_runtime.h>
#include <hip/hip_fp16.h>
#include <cstddef>
#include <cstdint>

constexpr int DIMS = 128;
constexpr float BN_EPS = 1e-5f;
constexpr int NSH = 64;  // stat shadow copies (kills same-address atomic serialization)

typedef _Float16 f16x8 __attribute__((ext_vector_type(8)));
typedef float f32x4 __attribute__((ext_vector_type(4)));

static __device__ __forceinline__ f16x8 as_f16x8(uint4 u) {
  union { uint4 u; f16x8 h; } x; x.u = u; return x.h;
}

// ---------------- utility ----------------
__global__ void zero_k(int* __restrict__ ip, size_t ni, float* __restrict__ fp, size_t nf) {
  size_t i = (size_t)blockIdx.x * blockDim.x + threadIdx.x;
  if (i < ni) ip[i] = 0;
  if (i < nf) fp[i] = 0.f;
}

// fp32 -> fp16 conversion with dn pre-scale: Xp[s] = dn[s] * nfeat[s]
__global__ void cvt_k(const float* __restrict__ in, uint32_t* __restrict__ out,
                      const float* __restrict__ dn, size_t n64) {
  size_t i = (size_t)blockIdx.x * blockDim.x + threadIdx.x;
  size_t stride = (size_t)gridDim.x * blockDim.x;
  const float2* in2 = (const float2*)in;
  for (; i < n64; i += stride) {
    float d = dn[i >> 6];
    float2 v = in2[i];
    __half2 h = __floats2half2_rn(v.x * d, v.y * d);
    out[i] = *(const uint32_t*)&h;
  }
}

__global__ void deg_count_k(const int* __restrict__ dst, int* __restrict__ deg, int e) {
  int i = blockIdx.x * blockDim.x + threadIdx.x;
  if (i < e) atomicAdd(&deg[dst[i]], 1);
}

__global__ void dnorm_k(const int* __restrict__ deg, float* __restrict__ dn, int n) {
  int i = blockIdx.x * blockDim.x + threadIdx.x;
  if (i < n) dn[i] = rsqrtf(fmaxf((float)deg[i], 1.0f));
}

// wsum[n] = sum_{s in in(n)} dn[s]
__global__ void wsum_k(const int* __restrict__ src, const int* __restrict__ dst,
                       const float* __restrict__ dn, float* __restrict__ ws, int e) {
  int i = blockIdx.x * blockDim.x + threadIdx.x;
  if (i < e) atomicAdd(&ws[dst[i]], dn[src[i]]);
}

// ---------------- CSR build: 2-level exclusive scan of degrees ----------------
__global__ void scan1_k(const int* __restrict__ deg, int* __restrict__ bsum, int n) {
  __shared__ int lds[256];
  int t = threadIdx.x;
  int base = blockIdx.x * 1024;
  int s = 0;
  for (int i = t; i < 1024; i += 256) {
    int idx = base + i;
    s += (idx < n) ? deg[idx] : 0;
  }
  lds[t] = s; __syncthreads();
  for (int off = 128; off > 0; off >>= 1) {
    if (t < off) lds[t] += lds[t + off];
    __syncthreads();
  }
  if (t == 0) bsum[blockIdx.x] = lds[0];
}

__global__ void scan2_k(int* __restrict__ bsum, int nb, int* __restrict__ row_off, int n, int e) {
  __shared__ int lds[256];
  int t = threadIdx.x;
  int v = (t < nb) ? bsum[t] : 0;
  lds[t] = v; __syncthreads();
  for (int off = 1; off < 256; off <<= 1) {
    int add = (t >= off) ? lds[t - off] : 0;
    __syncthreads();
    lds[t] += add;
    __syncthreads();
  }
  if (t < nb) bsum[t] = lds[t] - v;  // exclusive base per chunk
  if (t == 0) row_off[n] = e;
}

__global__ void scan3_k(const int* __restrict__ deg, const int* __restrict__ bsum,
                        int* __restrict__ row_off, int n) {
  __shared__ int lds[256];
  int t = threadIdx.x;
  int base = blockIdx.x * 1024 + t * 4;
  int e0 = (base + 0 < n) ? deg[base + 0] : 0;
  int e1 = (base + 1 < n) ? deg[base + 1] : 0;
  int e2 = (base + 2 < n) ? deg[base + 2] : 0;
  int e3 = (base + 3 < n) ? deg[base + 3] : 0;
  int ts = e0 + e1 + e2 + e3;
  lds[t] = ts; __syncthreads();
  for (int off = 1; off < 256; off <<= 1) {
    int add = (t >= off) ? lds[t - off] : 0;
    __syncthreads();
    lds[t] += add;
    __syncthreads();
  }
  int ex = lds[t] - ts + bsum[blockIdx.x];
  if (base + 0 < n) row_off[base + 0] = ex;
  ex += e0;
  if (base + 1 < n) row_off[base + 1] = ex;
  ex += e1;
  if (base + 2 < n) row_off[base + 2] = ex;
  ex += e2;
  if (base + 3 < n) row_off[base + 3] = ex;
}

__global__ void build_adj_k(const int* __restrict__ src, const int* __restrict__ dst,
                            const int* __restrict__ row_off, int* __restrict__ cursor,
                            int* __restrict__ adj, int e) {
  int i = blockIdx.x * blockDim.x + threadIdx.x;
  if (i < e) {
    int dn = dst[i];
    int p = atomicAdd(&cursor[dn], 1);
    adj[row_off[dn] + p] = src[i];
  }
}

// ---------------- propagation hop: one WAVE per node ----------------
// 4 edge-groups x 16 feature-lanes; lane owns 8 features (16B uint4 per row);
// 8-deep unroll per group -> 32 edges in flight per wave.
// AFF=false (hop1): acc = sum Xp[s]; v = dn*acc (stats); store W1 = dn*v = dn^2*acc.
// AFF=true  (hop2): acc = sum W1[s]; v = dn*(a*acc + b*wsum[n]) (stats); store v.
template <bool AFF>
__global__ __launch_bounds__(256) void gather_k(
    const uint4* __restrict__ Xu, uint4* __restrict__ Yout,
    const int* __restrict__ row_off, const int* __restrict__ adj,
    const float* __restrict__ dn, const float* __restrict__ wsum,
    const float* __restrict__ a, const float* __restrict__ b,
    float* __restrict__ sumS, float* __restrict__ sqS, int n) {
  int tid = threadIdx.x;
  int l = tid & 63, w = tid >> 6;
  int grp = l >> 4;       // edge group 0..3
  int fl = l & 15;        // feature-lane: features fl*8 .. fl*8+7
  int f0 = fl * 8;
  int node = blockIdx.x * 4 + w;  // wave-uniform
  bool active = node < n;

  float v[8];
  if (active) {
    int j0 = row_off[node], j1 = row_off[node + 1];
    float acc[8] = {0.f, 0.f, 0.f, 0.f, 0.f, 0.f, 0.f, 0.f};
    for (int j = j0; j < j1; j += 32) {
      uint4 xv[8];
#pragma unroll
      for (int t = 0; t < 8; ++t) {
        int jj = j + t * 4 + grp;
        xv[t] = make_uint4(0u, 0u, 0u, 0u);
        if (jj < j1) {
          int sj = adj[jj];
          xv[t] = Xu[(size_t)sj * 16 + fl];
        }
      }
#pragma unroll
      for (int t = 0; t < 8; ++t) {
        const __half2* h = (const __half2*)&xv[t];
#pragma unroll
        for (int q = 0; q < 4; ++q) {
          float2 x = __half22float2(h[q]);
          acc[2 * q] += x.x;
          acc[2 * q + 1] += x.y;
        }
      }
    }
    // reduce across the 4 edge groups (butterfly; all lanes end with totals)
#pragma unroll
    for (int q = 0; q < 8; ++q) {
      acc[q] += __shfl_xor(acc[q], 16);
      acc[q] += __shfl_xor(acc[q], 32);
    }
    float dnn = dn[node];
    if constexpr (AFF) {
      float wsn = wsum[node];
#pragma unroll
      for (int q = 0; q < 8; ++q)
        v[q] = dnn * fmaf(a[f0 + q], acc[q], b[f0 + q] * wsn);
      if (grp == 0) {
        __half2 hh[4];
#pragma unroll
        for (int q = 0; q < 4; ++q) hh[q] = __floats2half2_rn(v[2 * q], v[2 * q + 1]);
        Yout[(size_t)node * 16 + fl] = *(const uint4*)hh;
      }
    } else {
#pragma unroll
      for (int q = 0; q < 8; ++q) v[q] = dnn * acc[q];
      if (grp == 0) {
        __half2 hh[4];
#pragma unroll
        for (int q = 0; q < 4; ++q)
          hh[q] = __floats2half2_rn(v[2 * q] * dnn, v[2 * q + 1] * dnn);  // W1 = dn^2*acc
        Yout[(size_t)node * 16 + fl] = *(const uint4*)hh;
      }
    }
  }
  // block stats: per-wave slab (written by grp-0 lanes), then cross-wave reduce
  __shared__ float sred[4][128], qred[4][128];
  if (active) {
    if (grp == 0) {
#pragma unroll
      for (int q = 0; q < 8; ++q) {
        sred[w][f0 + q] = v[q];
        qred[w][f0 + q] = v[q] * v[q];
      }
    }
  } else {
    sred[w][l] = 0.f; sred[w][64 + l] = 0.f;
    qred[w][l] = 0.f; qred[w][64 + l] = 0.f;
  }
  __syncthreads();
  int f = tid & 127;
  int sh = blockIdx.x & (NSH - 1);
  if (tid < 128) {
    float s = sred[0][f] + sred[1][f] + sred[2][f] + sred[3][f];
    atomicAdd(&sumS[sh * DIMS + f], s);
  } else {
    float q = qred[0][f] + qred[1][f] + qred[2][f] + qred[3][f];
    atomicAdd(&sqS[sh * DIMS + f], q);
  }
}

// ---------------- BN affine coefficients (reduces NSH shadow copies) ----------------
__global__ void affine_k(const float* __restrict__ sum, const float* __restrict__ sq,
                         const float* __restrict__ gamma, const float* __restrict__ beta,
                         float* __restrict__ a, float* __restrict__ b, float invn) {
  int d = threadIdx.x;
  float s = 0.f, q = 0.f;
  for (int k = 0; k < NSH; ++k) { s += sum[k * DIMS + d]; q += sq[k * DIMS + d]; }
  float mu = s * invn;
  float var = q * invn - mu * mu;
  float rs = rsqrtf(var + BN_EPS);
  float ad = rs * gamma[d];
  a[d] = ad;
  b[d] = beta[d] - mu * ad;
}

// fold pre-matmul affine into weights, TRANSPOSED fp16:
// Wt[o][d] = (half)(a2[d]*W[d][o]);  cp[o] = sum_d b2[d]*W[d][o] + cb[o]
__global__ void foldw_k(const float* __restrict__ W, const float* __restrict__ cb,
                        const float* __restrict__ a2, const float* __restrict__ b2,
                        __half* __restrict__ Wt, float* __restrict__ cp) {
  int o = blockIdx.x;
  int d = threadIdx.x;
  float w = W[d * DIMS + o];
  Wt[o * DIMS + d] = __float2half(a2[d] * w);
  __shared__ float red[128];
  red[d] = b2[d] * w;
  __syncthreads();
  for (int off = 64; off > 0; off >>= 1) {
    if (d < off) red[d] += red[d + off];
    __syncthreads();
  }
  if (d == 0) cp[o] = red[0] + cb[o];
}

// ---------------- Z = X @ W + cp via MFMA (fp16 in/out, f32 accum, fused BN stats) ----
// Wave computes 16 rows x 128 cols. A: lane row=l&15, k=(l>>4)*8+j.
// B from Wt[o][d]: lane col=l&15, k=(l>>4)*8+j -> contiguous 16B reads.
// C/D: col=l&15, row=(l>>4)*4+reg.
__global__ __launch_bounds__(256) void matmul_k(
    const uint4* __restrict__ X, const uint4* __restrict__ Wt,
    const float* __restrict__ cp, __half* __restrict__ Z,
    float* __restrict__ sumS, float* __restrict__ sqS, int n) {
  int tid = threadIdx.x;
  int l = tid & 63, w = tid >> 6;
  int rowg = l & 15;  // A-row / B-col / D-col within tile
  int kg = l >> 4;    // k-group
  int r0 = (blockIdx.x * 4 + w) * 16;
  bool active = r0 < n;

  __shared__ float sred[4][128], qred[4][128];
  float svals[8], qvals[8];

  if (active) {
    f32x4 acc[8] = {};
    const uint4* xrow = X + (size_t)(r0 + rowg) * 16;
    bool arow_ok = (r0 + rowg) < n;
#pragma unroll
    for (int kk = 0; kk < 4; ++kk) {
      uint4 au = arow_ok ? xrow[kk * 4 + kg] : make_uint4(0u, 0u, 0u, 0u);
      f16x8 afr = as_f16x8(au);
#pragma unroll
      for (int c = 0; c < 8; ++c) {
        f16x8 bfr = as_f16x8(Wt[(size_t)(c * 16 + rowg) * 16 + kk * 4 + kg]);
        acc[c] = __builtin_amdgcn_mfma_f32_16x16x32_f16(afr, bfr, acc[c], 0, 0, 0);
      }
    }
    // epilogue: +cp, stats, scalar fp16 stores
#pragma unroll
    for (int c = 0; c < 8; ++c) {
      float cpv = cp[c * 16 + rowg];
      float s = 0.f, q = 0.f;
#pragma unroll
      for (int r = 0; r < 4; ++r) {
        int row = r0 + kg * 4 + r;
        float vv = acc[c][r] + cpv;
        bool ok = row < n;
        vv = ok ? vv : 0.f;
        s += vv; q += vv * vv;
        if (ok) Z[(size_t)row * DIMS + c * 16 + rowg] = __float2half(vv);
      }
      s += __shfl_xor(s, 16); s += __shfl_xor(s, 32);
      q += __shfl_xor(q, 16); q += __shfl_xor(q, 32);
      svals[c] = s; qvals[c] = q;
    }
  }
  if (active) {
    if (kg == 0) {
#pragma unroll
      for (int c = 0; c < 8; ++c) {
        sred[w][c * 16 + rowg] = svals[c];
        qred[w][c * 16 + rowg] = qvals[c];
      }
    }
  } else {
    sred[w][l] = 0.f; sred[w][64 + l] = 0.f;
    qred[w][l] = 0.f; qred[w][64 + l] = 0.f;
  }
  __syncthreads();
  int f = tid & 127;
  int sh = blockIdx.x & (NSH - 1);
  if (tid < 128) {
    float s = sred[0][f] + sred[1][f] + sred[2][f] + sred[3][f];
    atomicAdd(&sumS[sh * DIMS + f], s);
  } else {
    float q = qred[0][f] + qred[1][f] + qred[2][f] + qred[3][f];
    atomicAdd(&sqS[sh * DIMS + f], q);
  }
}

// ---------------- graph segment starts (node2graph is sorted) ----------------
__global__ void gstart_k(const int* __restrict__ n2g, int* __restrict__ gstart, int n, int G) {
  int i = blockIdx.x * blockDim.x + threadIdx.x;
  if (i >= n) return;
  int g = n2g[i];
  int gp = (i == 0) ? -1 : n2g[i - 1];
  for (int x = gp + 1; x <= g; ++x) gstart[x] = i;
  if (i == n - 1) {
    for (int x = g + 1; x <= G; ++x) gstart[x] = n;
  }
}

// ---------------- BN2-apply + relu + mean-pool + 128->2 projection ----------------
__global__ __launch_bounds__(256) void pool_pred_k(
    const uint4* __restrict__ Z, const int* __restrict__ gstart,
    const float* __restrict__ a3, const float* __restrict__ b3,
    const float* __restrict__ pw, const float* __restrict__ pb,
    float* __restrict__ out) {
  int g = blockIdx.x;
  int tid = threadIdx.x;
  int l = tid & 63, w = tid >> 6;
  int grp = l >> 4, fl = l & 15;
  int f0 = fl * 8;
  float av[8], bv[8];
#pragma unroll
  for (int q = 0; q < 8; ++q) { av[q] = a3[f0 + q]; bv[q] = b3[f0 + q]; }
  int s = gstart[g], e = gstart[g + 1];
  float rs[8] = {0.f, 0.f, 0.f, 0.f, 0.f, 0.f, 0.f, 0.f};
  for (int ni = s + w * 4 + grp; ni < e; ni += 16) {
    uint4 zv = Z[(size_t)ni * 16 + fl];
    const __half2* h = (const __half2*)&zv;
#pragma unroll
    for (int q = 0; q < 4; ++q) {
      float2 z = __half22float2(h[q]);
      rs[2 * q] += fmaxf(fmaf(z.x, av[2 * q], bv[2 * q]), 0.f);
      rs[2 * q + 1] += fmaxf(fmaf(z.y, av[2 * q + 1], bv[2 * q + 1]), 0.f);
    }
  }
  float p0 = 0.f, p1 = 0.f;
#pragma unroll
  for (int q = 0; q < 8; ++q) {
    p0 += rs[q] * pw[(f0 + q) * 2 + 0];
    p1 += rs[q] * pw[(f0 + q) * 2 + 1];
  }
  __shared__ float r[2][256];
  r[0][tid] = p0; r[1][tid] = p1;
  __syncthreads();
  for (int off = 128; off > 0; off >>= 1) {
    if (tid < off) { r[0][tid] += r[0][tid + off]; r[1][tid] += r[1][tid + off]; }
    __syncthreads();
  }
  if (tid == 0) {
    float inv = 1.f / fmaxf((float)(e - s), 1.f);
    out[g * 2 + 0] = r[0][0] * inv + pb[0];
    out[g * 2 + 1] = r[1][0] * inv + pb[1];
  }
}

// ---------------- host launch ----------------
extern "C" void kernel_launch(void* const* d_in, const int* in_sizes, int n_in,
                              void* d_out, int out_size, void* d_ws, size_t ws_size,
                              hipStream_t stream) {
  const float* nfeat  = (const float*)d_in[0];
  const int*   src    = (const int*)d_in[1];
  const int*   dst    = (const int*)d_in[2];
  const int*   n2g    = (const int*)d_in[3];
  // d_in[4] = num_graphs (device scalar) — derived from out_size instead
  const float* conv_w = (const float*)d_in[5];
  const float* conv_b = (const float*)d_in[6];
  const float* gamma1 = (const float*)d_in[7];
  const float* beta1  = (const float*)d_in[8];
  const float* gamma2 = (const float*)d_in[9];
  const float* beta2  = (const float*)d_in[10];
  const float* pred_w = (const float*)d_in[11];
  const float* pred_b = (const float*)d_in[12];
  float* out = (float*)d_out;
  (void)n_in; (void)ws_size;

  const int n = in_sizes[0] / DIMS;
  const int e = in_sizes[1];
  const int g = out_size / 2;

  char* p = (char*)d_ws;
  auto alloc = [&](size_t bytes) { char* r = p; p += (bytes + 255) & ~(size_t)255; return r; };
  uint32_t* Xp  = (uint32_t*)alloc((size_t)n * 64 * 4);  // dn-scaled input rows (fp16)
  uint4*    W1  = (uint4*)alloc((size_t)n * 64 * 4);     // dn^2-scaled h1 rows (fp16)
  uint4*    Y2  = (uint4*)alloc((size_t)n * 64 * 4);     // p2 rows (fp16)
  __half*   Zh  = (__half*)alloc((size_t)n * 64 * 4);    // matmul output rows (fp16)
  float* dnorm = (float*)alloc((size_t)n * 4);
  float* stat  = (float*)alloc(((size_t)6 * NSH * DIMS + n) * 4);  // stats + wsum
  float* wsum  = stat + 6 * NSH * DIMS;
  float* affA  = (float*)alloc(3 * DIMS * 4);
  float* affB  = (float*)alloc(3 * DIMS * 4);
  __half* Wt   = (__half*)alloc(DIMS * DIMS * 2);
  float* cp    = (float*)alloc(DIMS * 4);
  int* deg_i   = (int*)alloc((size_t)n * 2 * 4);  // deg + cursor
  int* cursor  = deg_i + n;
  int* row_off = (int*)alloc(((size_t)n + 1) * 4);
  int* adj     = (int*)alloc((size_t)e * 4);
  int* bsum    = (int*)alloc(2048 * 4);
  int* gstart  = (int*)alloc(((size_t)g + 1) * 4);

  const int SLAB = NSH * DIMS;
  float* S0 = stat + 0 * SLAB; float* Q0 = stat + 1 * SLAB;
  float* S1 = stat + 2 * SLAB; float* Q1 = stat + 3 * SLAB;
  float* S2 = stat + 4 * SLAB; float* Q2 = stat + 5 * SLAB;

  const int nb = (n + 1023) / 1024;  // <= 256 required (n <= 262144)
  const float invn = 1.0f / (float)n;
  const int gb = (n + 3) / 4;        // one wave per node, 4 per block

  size_t zf = (size_t)6 * SLAB + n;  // zero stats + wsum
  size_t zmax = (size_t)2 * n > zf ? (size_t)2 * n : zf;
  zero_k<<<dim3((zmax + 255) / 256), dim3(256), 0, stream>>>(deg_i, (size_t)2 * n, stat, zf);
  deg_count_k<<<dim3((e + 255) / 256), dim3(256), 0, stream>>>(dst, deg_i, e);
  dnorm_k<<<dim3((n + 255) / 256), dim3(256), 0, stream>>>(deg_i, dnorm, n);
  cvt_k<<<dim3(2048), dim3(256), 0, stream>>>(nfeat, Xp, dnorm, (size_t)n * 64);
  wsum_k<<<dim3((e + 255) / 256), dim3(256), 0, stream>>>(src, dst, dnorm, wsum, e);
  scan1_k<<<dim3(nb), dim3(256), 0, stream>>>(deg_i, bsum, n);
  scan2_k<<<dim3(1), dim3(256), 0, stream>>>(bsum, nb, row_off, n, e);
  scan3_k<<<dim3(nb), dim3(256), 0, stream>>>(deg_i, bsum, row_off, n);
  build_adj_k<<<dim3((e + 255) / 256), dim3(256), 0, stream>>>(src, dst, row_off, cursor, adj, e);

  // hop 1: Xp -> W1 (stats of p1 -> S0/Q0)
  gather_k<false><<<dim3(gb), dim3(256), 0, stream>>>(
      (const uint4*)Xp, W1, row_off, adj, dnorm, wsum, nullptr, nullptr, S0, Q0, n);
  affine_k<<<dim3(1), dim3(DIMS), 0, stream>>>(S0, Q0, gamma1, beta1, affA + 0, affB + 0, invn);
  // hop 2: W1 -> Y2 = p2 (stats -> S1/Q1)
  gather_k<true><<<dim3(gb), dim3(256), 0, stream>>>(
      W1, Y2, row_off, adj, dnorm, wsum, affA + 0, affB + 0, S1, Q1, n);
  affine_k<<<dim3(1), dim3(DIMS), 0, stream>>>(S1, Q1, gamma1, beta1, affA + DIMS, affB + DIMS, invn);
  // fold stage-1 affine into transposed fp16 weights, then MFMA matmul (stats -> S2/Q2)
  foldw_k<<<dim3(DIMS), dim3(DIMS), 0, stream>>>(conv_w, conv_b, affA + DIMS, affB + DIMS, Wt, cp);
  matmul_k<<<dim3((n + 63) / 64), dim3(256), 0, stream>>>(
      Y2, (const uint4*)Wt, cp, Zh, S2, Q2, n);
  affine_k<<<dim3(1), dim3(DIMS), 0, stream>>>(S2, Q2, gamma2, beta2, affA + 2 * DIMS, affB + 2 * DIMS, invn);
  // pooling + prediction
  gstart_k<<<dim3((n + 255) / 256), dim3(256), 0, stream>>>(n2g, gstart, n, g);
  pool_pred_k<<<dim3(g), dim3(256), 0, stream>>>((const uint4*)Zh, gstart,
                                                 affA + 2 * DIMS, affB + 2 * DIMS,
                                                 pred_w, pred_b, out);
}

// Round 5
// 477.107 us; speedup vs baseline: 1.0619x; 1.0619x over previous
//
#include <hip/hip_runtime.h>
#include <hip/hip_fp16.h>
#include <cstddef>
#include <cstdint>

constexpr int DIMS = 128;
constexpr float BN_EPS = 1e-5f;
constexpr int NSH = 64;   // stat shadow copies
constexpr int GB = 2048;  // gather grid blocks (x4 waves = 8192 waves)

typedef _Float16 f16x8 __attribute__((ext_vector_type(8)));
typedef float f32x4 __attribute__((ext_vector_type(4)));

static __device__ __forceinline__ f16x8 as_f16x8(uint4 u) {
  union { uint4 u; f16x8 h; } x; x.u = u; return x.h;
}

// ---------------- utility ----------------
__global__ void zero_k(int* __restrict__ ip, size_t ni, float* __restrict__ fp, size_t nf) {
  size_t i = (size_t)blockIdx.x * blockDim.x + threadIdx.x;
  if (i < ni) ip[i] = 0;
  if (i < nf) fp[i] = 0.f;
}

// fp32 -> fp16 conversion with dn pre-scale: Xp[s] = dn[s] * nfeat[s]
__global__ void cvt_k(const float* __restrict__ in, uint32_t* __restrict__ out,
                      const float* __restrict__ dn, size_t n64) {
  size_t i = (size_t)blockIdx.x * blockDim.x + threadIdx.x;
  size_t stride = (size_t)gridDim.x * blockDim.x;
  const float2* in2 = (const float2*)in;
  for (; i < n64; i += stride) {
    float d = dn[i >> 6];
    float2 v = in2[i];
    __half2 h = __floats2half2_rn(v.x * d, v.y * d);
    out[i] = *(const uint32_t*)&h;
  }
}

__global__ void deg_count_k(const int* __restrict__ dst, int* __restrict__ deg, int e) {
  int i = blockIdx.x * blockDim.x + threadIdx.x;
  if (i < e) atomicAdd(&deg[dst[i]], 1);
}

__global__ void dnorm_k(const int* __restrict__ deg, float* __restrict__ dn, int n) {
  int i = blockIdx.x * blockDim.x + threadIdx.x;
  if (i < n) dn[i] = rsqrtf(fmaxf((float)deg[i], 1.0f));
}

// wsum[n] = sum_{s in in(n)} dn[s]
__global__ void wsum_k(const int* __restrict__ src, const int* __restrict__ dst,
                       const float* __restrict__ dn, float* __restrict__ ws, int e) {
  int i = blockIdx.x * blockDim.x + threadIdx.x;
  if (i < e) atomicAdd(&ws[dst[i]], dn[src[i]]);
}

// ---------------- CSR build: 2-level exclusive scan of degrees ----------------
__global__ void scan1_k(const int* __restrict__ deg, int* __restrict__ bsum, int n) {
  __shared__ int lds[256];
  int t = threadIdx.x;
  int base = blockIdx.x * 1024;
  int s = 0;
  for (int i = t; i < 1024; i += 256) {
    int idx = base + i;
    s += (idx < n) ? deg[idx] : 0;
  }
  lds[t] = s; __syncthreads();
  for (int off = 128; off > 0; off >>= 1) {
    if (t < off) lds[t] += lds[t + off];
    __syncthreads();
  }
  if (t == 0) bsum[blockIdx.x] = lds[0];
}

__global__ void scan2_k(int* __restrict__ bsum, int nb, int* __restrict__ row_off, int n, int e) {
  __shared__ int lds[256];
  int t = threadIdx.x;
  int v = (t < nb) ? bsum[t] : 0;
  lds[t] = v; __syncthreads();
  for (int off = 1; off < 256; off <<= 1) {
    int add = (t >= off) ? lds[t - off] : 0;
    __syncthreads();
    lds[t] += add;
    __syncthreads();
  }
  if (t < nb) bsum[t] = lds[t] - v;  // exclusive base per chunk
  if (t == 0) row_off[n] = e;
}

__global__ void scan3_k(const int* __restrict__ deg, const int* __restrict__ bsum,
                        int* __restrict__ row_off, int n) {
  __shared__ int lds[256];
  int t = threadIdx.x;
  int base = blockIdx.x * 1024 + t * 4;
  int e0 = (base + 0 < n) ? deg[base + 0] : 0;
  int e1 = (base + 1 < n) ? deg[base + 1] : 0;
  int e2 = (base + 2 < n) ? deg[base + 2] : 0;
  int e3 = (base + 3 < n) ? deg[base + 3] : 0;
  int ts = e0 + e1 + e2 + e3;
  lds[t] = ts; __syncthreads();
  for (int off = 1; off < 256; off <<= 1) {
    int add = (t >= off) ? lds[t - off] : 0;
    __syncthreads();
    lds[t] += add;
    __syncthreads();
  }
  int ex = lds[t] - ts + bsum[blockIdx.x];
  if (base + 0 < n) row_off[base + 0] = ex;
  ex += e0;
  if (base + 1 < n) row_off[base + 1] = ex;
  ex += e1;
  if (base + 2 < n) row_off[base + 2] = ex;
  ex += e2;
  if (base + 3 < n) row_off[base + 3] = ex;
}

__global__ void build_adj_k(const int* __restrict__ src, const int* __restrict__ dst,
                            const int* __restrict__ row_off, int* __restrict__ cursor,
                            int* __restrict__ adj, int e) {
  int i = blockIdx.x * blockDim.x + threadIdx.x;
  if (i < e) {
    int dn = dst[i];
    int p = atomicAdd(&cursor[dn], 1);
    adj[row_off[dn] + p] = src[i];
  }
}

// ---------------- propagation hop: grid-stride, one WAVE per node at a time -------
// Lane owns 2 features (half2 row element). 8-deep edge pipeline.
// AFF=false (hop1): acc = sum Xp[s]; v = dn*acc (stats); store W1 = dn*v = dn^2*acc.
// AFF=true  (hop2): acc = sum W1[s]; v = dn*(a*acc + b*wsum[n]) (stats); store v.
// Stats accumulate in registers across all nodes of the wave; one block epilogue.
template <bool AFF>
__global__ __launch_bounds__(256) void gather_k(
    const uint32_t* __restrict__ Xu, uint32_t* __restrict__ Yout,
    const int* __restrict__ row_off, const int* __restrict__ adj,
    const float* __restrict__ dn, const float* __restrict__ wsum,
    const float* __restrict__ a, const float* __restrict__ b,
    float* __restrict__ sumS, float* __restrict__ sqS, int n, int nwaves) {
  int tid = threadIdx.x;
  int l = tid & 63, w = tid >> 6;
  int wid = blockIdx.x * 4 + w;  // wave-uniform
  int f0 = 2 * l;
  float af0 = 1.f, bf0 = 0.f, af1 = 1.f, bf1 = 0.f;
  if (AFF) { af0 = a[f0]; bf0 = b[f0]; af1 = a[f0 + 1]; bf1 = b[f0 + 1]; }
  float s0 = 0.f, s1 = 0.f, q0 = 0.f, q1 = 0.f;

  for (int node = wid; node < n; node += nwaves) {
    int j0 = row_off[node], j1 = row_off[node + 1];
    float acc0 = 0.f, acc1 = 0.f;
    for (int j = j0; j < j1; j += 8) {
      uint32_t xv[8];
#pragma unroll
      for (int t = 0; t < 8; ++t) {
        int jj = j + t;
        xv[t] = 0u;
        if (jj < j1) {  // wave-uniform branch
          int sj = adj[jj];
          xv[t] = Xu[(size_t)sj * 64 + l];
        }
      }
#pragma unroll
      for (int t = 0; t < 8; ++t) {
        float2 x = __half22float2(*(const __half2*)&xv[t]);
        acc0 += x.x;
        acc1 += x.y;
      }
    }
    float dnn = dn[node];
    float v0, v1;
    if constexpr (AFF) {
      float wsn = wsum[node];
      v0 = dnn * fmaf(af0, acc0, bf0 * wsn);
      v1 = dnn * fmaf(af1, acc1, bf1 * wsn);
      __half2 hv = __floats2half2_rn(v0, v1);
      Yout[(size_t)node * 64 + l] = *(const uint32_t*)&hv;
    } else {
      v0 = dnn * acc0;
      v1 = dnn * acc1;
      __half2 hv = __floats2half2_rn(v0 * dnn, v1 * dnn);  // W1 = dn^2*acc
      Yout[(size_t)node * 64 + l] = *(const uint32_t*)&hv;
    }
    s0 += v0; s1 += v1; q0 += v0 * v0; q1 += v1 * v1;
  }

  // block epilogue: LDS cross-wave reduce, then 256 lane-atomics per block
  __shared__ float red[4][256];
  red[w][l] = s0; red[w][64 + l] = s1; red[w][128 + l] = q0; red[w][192 + l] = q1;
  __syncthreads();
  float t = red[0][tid] + red[1][tid] + red[2][tid] + red[3][tid];
  int comp = tid >> 6, li = tid & 63;
  int sh = blockIdx.x & (NSH - 1);
  float* dstp = ((comp & 2) ? sqS : sumS) + sh * DIMS;
  atomicAdd(&dstp[2 * li + (comp & 1)], t);
}

// ---------------- BN affine coefficients (reduces NSH shadow copies) ----------------
__global__ void affine_k(const float* __restrict__ sum, const float* __restrict__ sq,
                         const float* __restrict__ gamma, const float* __restrict__ beta,
                         float* __restrict__ a, float* __restrict__ b, float invn) {
  int d = threadIdx.x;
  float s = 0.f, q = 0.f;
  for (int k = 0; k < NSH; ++k) { s += sum[k * DIMS + d]; q += sq[k * DIMS + d]; }
  float mu = s * invn;
  float var = q * invn - mu * mu;
  float rs = rsqrtf(var + BN_EPS);
  float ad = rs * gamma[d];
  a[d] = ad;
  b[d] = beta[d] - mu * ad;
}

// fold pre-matmul affine into weights, TRANSPOSED fp16:
// Wt[o][d] = (half)(a2[d]*W[d][o]);  cp[o] = sum_d b2[d]*W[d][o] + cb[o]
__global__ void foldw_k(const float* __restrict__ W, const float* __restrict__ cb,
                        const float* __restrict__ a2, const float* __restrict__ b2,
                        __half* __restrict__ Wt, float* __restrict__ cp) {
  int o = blockIdx.x;
  int d = threadIdx.x;
  float w = W[d * DIMS + o];
  Wt[o * DIMS + d] = __float2half(a2[d] * w);
  __shared__ float red[128];
  red[d] = b2[d] * w;
  __syncthreads();
  for (int off = 64; off > 0; off >>= 1) {
    if (d < off) red[d] += red[d + off];
    __syncthreads();
  }
  if (d == 0) cp[o] = red[0] + cb[o];
}

// ---------------- Z = X @ W + cp via MFMA (fp16 in/out, f32 accum, fused BN stats) ----
// Wave computes 16 rows x 128 cols. A: lane row=l&15, k=(l>>4)*8+j.
// B from Wt[o][d]: lane col=l&15, k=(l>>4)*8+j -> contiguous 16B reads.
// C/D: col=l&15, row=(l>>4)*4+reg.
__global__ __launch_bounds__(256) void matmul_k(
    const uint4* __restrict__ X, const uint4* __restrict__ Wt,
    const float* __restrict__ cp, __half* __restrict__ Z,
    float* __restrict__ sumS, float* __restrict__ sqS, int n) {
  int tid = threadIdx.x;
  int l = tid & 63, w = tid >> 6;
  int rowg = l & 15;  // A-row / B-col / D-col within tile
  int kg = l >> 4;    // k-group
  int r0 = (blockIdx.x * 4 + w) * 16;
  bool active = r0 < n;

  __shared__ float sred[4][128], qred[4][128];
  float svals[8], qvals[8];

  if (active) {
    f32x4 acc[8] = {};
    const uint4* xrow = X + (size_t)(r0 + rowg) * 16;
    bool arow_ok = (r0 + rowg) < n;
#pragma unroll
    for (int kk = 0; kk < 4; ++kk) {
      uint4 au = arow_ok ? xrow[kk * 4 + kg] : make_uint4(0u, 0u, 0u, 0u);
      f16x8 afr = as_f16x8(au);
#pragma unroll
      for (int c = 0; c < 8; ++c) {
        f16x8 bfr = as_f16x8(Wt[(size_t)(c * 16 + rowg) * 16 + kk * 4 + kg]);
        acc[c] = __builtin_amdgcn_mfma_f32_16x16x32_f16(afr, bfr, acc[c], 0, 0, 0);
      }
    }
    // epilogue: +cp, stats, scalar fp16 stores
#pragma unroll
    for (int c = 0; c < 8; ++c) {
      float cpv = cp[c * 16 + rowg];
      float s = 0.f, q = 0.f;
#pragma unroll
      for (int r = 0; r < 4; ++r) {
        int row = r0 + kg * 4 + r;
        float vv = acc[c][r] + cpv;
        bool ok = row < n;
        vv = ok ? vv : 0.f;
        s += vv; q += vv * vv;
        if (ok) Z[(size_t)row * DIMS + c * 16 + rowg] = __float2half(vv);
      }
      s += __shfl_xor(s, 16); s += __shfl_xor(s, 32);
      q += __shfl_xor(q, 16); q += __shfl_xor(q, 32);
      svals[c] = s; qvals[c] = q;
    }
  }
  if (active) {
    if (kg == 0) {
#pragma unroll
      for (int c = 0; c < 8; ++c) {
        sred[w][c * 16 + rowg] = svals[c];
        qred[w][c * 16 + rowg] = qvals[c];
      }
    }
  } else {
    sred[w][l] = 0.f; sred[w][64 + l] = 0.f;
    qred[w][l] = 0.f; qred[w][64 + l] = 0.f;
  }
  __syncthreads();
  int f = tid & 127;
  int sh = blockIdx.x & (NSH - 1);
  if (tid < 128) {
    float s = sred[0][f] + sred[1][f] + sred[2][f] + sred[3][f];
    atomicAdd(&sumS[sh * DIMS + f], s);
  } else {
    float q = qred[0][f] + qred[1][f] + qred[2][f] + qred[3][f];
    atomicAdd(&sqS[sh * DIMS + f], q);
  }
}

// ---------------- graph segment starts (node2graph is sorted) ----------------
__global__ void gstart_k(const int* __restrict__ n2g, int* __restrict__ gstart, int n, int G) {
  int i = blockIdx.x * blockDim.x + threadIdx.x;
  if (i >= n) return;
  int g = n2g[i];
  int gp = (i == 0) ? -1 : n2g[i - 1];
  for (int x = gp + 1; x <= g; ++x) gstart[x] = i;
  if (i == n - 1) {
    for (int x = g + 1; x <= G; ++x) gstart[x] = n;
  }
}

// ---------------- BN2-apply + relu + mean-pool + 128->2 projection ----------------
__global__ __launch_bounds__(256) void pool_pred_k(
    const uint4* __restrict__ Z, const int* __restrict__ gstart,
    const float* __restrict__ a3, const float* __restrict__ b3,
    const float* __restrict__ pw, const float* __restrict__ pb,
    float* __restrict__ out) {
  int g = blockIdx.x;
  int tid = threadIdx.x;
  int l = tid & 63, w = tid >> 6;
  int grp = l >> 4, fl = l & 15;
  int f0 = fl * 8;
  float av[8], bv[8];
#pragma unroll
  for (int q = 0; q < 8; ++q) { av[q] = a3[f0 + q]; bv[q] = b3[f0 + q]; }
  int s = gstart[g], e = gstart[g + 1];
  float rs[8] = {0.f, 0.f, 0.f, 0.f, 0.f, 0.f, 0.f, 0.f};
  for (int ni = s + w * 4 + grp; ni < e; ni += 16) {
    uint4 zv = Z[(size_t)ni * 16 + fl];
    const __half2* h = (const __half2*)&zv;
#pragma unroll
    for (int q = 0; q < 4; ++q) {
      float2 z = __half22float2(h[q]);
      rs[2 * q] += fmaxf(fmaf(z.x, av[2 * q], bv[2 * q]), 0.f);
      rs[2 * q + 1] += fmaxf(fmaf(z.y, av[2 * q + 1], bv[2 * q + 1]), 0.f);
    }
  }
  float p0 = 0.f, p1 = 0.f;
#pragma unroll
  for (int q = 0; q < 8; ++q) {
    p0 += rs[q] * pw[(f0 + q) * 2 + 0];
    p1 += rs[q] * pw[(f0 + q) * 2 + 1];
  }
  __shared__ float r[2][256];
  r[0][tid] = p0; r[1][tid] = p1;
  __syncthreads();
  for (int off = 128; off > 0; off >>= 1) {
    if (tid < off) { r[0][tid] += r[0][tid + off]; r[1][tid] += r[1][tid + off]; }
    __syncthreads();
  }
  if (tid == 0) {
    float inv = 1.f / fmaxf((float)(e - s), 1.f);
    out[g * 2 + 0] = r[0][0] * inv + pb[0];
    out[g * 2 + 1] = r[1][0] * inv + pb[1];
  }
}

// ---------------- host launch ----------------
extern "C" void kernel_launch(void* const* d_in, const int* in_sizes, int n_in,
                              void* d_out, int out_size, void* d_ws, size_t ws_size,
                              hipStream_t stream) {
  const float* nfeat  = (const float*)d_in[0];
  const int*   src    = (const int*)d_in[1];
  const int*   dst    = (const int*)d_in[2];
  const int*   n2g    = (const int*)d_in[3];
  // d_in[4] = num_graphs (device scalar) — derived from out_size instead
  const float* conv_w = (const float*)d_in[5];
  const float* conv_b = (const float*)d_in[6];
  const float* gamma1 = (const float*)d_in[7];
  const float* beta1  = (const float*)d_in[8];
  const float* gamma2 = (const float*)d_in[9];
  const float* beta2  = (const float*)d_in[10];
  const float* pred_w = (const float*)d_in[11];
  const float* pred_b = (const float*)d_in[12];
  float* out = (float*)d_out;
  (void)n_in; (void)ws_size;

  const int n = in_sizes[0] / DIMS;
  const int e = in_sizes[1];
  const int g = out_size / 2;

  char* p = (char*)d_ws;
  auto alloc = [&](size_t bytes) { char* r = p; p += (bytes + 255) & ~(size_t)255; return r; };
  uint32_t* Xp  = (uint32_t*)alloc((size_t)n * 64 * 4);  // dn-scaled input rows (fp16)
  uint32_t* W1  = (uint32_t*)alloc((size_t)n * 64 * 4);  // dn^2-scaled h1 rows (fp16)
  uint32_t* Y2  = (uint32_t*)alloc((size_t)n * 64 * 4);  // h2 rows (fp16)
  __half*   Zh  = (__half*)alloc((size_t)n * 64 * 4);    // matmul output rows (fp16)
  float* dnorm = (float*)alloc((size_t)n * 4);
  float* stat  = (float*)alloc(((size_t)6 * NSH * DIMS + n) * 4);  // stats + wsum
  float* wsum  = stat + 6 * NSH * DIMS;
  float* affA  = (float*)alloc(3 * DIMS * 4);
  float* affB  = (float*)alloc(3 * DIMS * 4);
  __half* Wt   = (__half*)alloc(DIMS * DIMS * 2);
  float* cp    = (float*)alloc(DIMS * 4);
  int* deg_i   = (int*)alloc((size_t)n * 2 * 4);  // deg + cursor
  int* cursor  = deg_i + n;
  int* row_off = (int*)alloc(((size_t)n + 1) * 4);
  int* adj     = (int*)alloc((size_t)e * 4);
  int* bsum    = (int*)alloc(2048 * 4);
  int* gstart  = (int*)alloc(((size_t)g + 1) * 4);

  const int SLAB = NSH * DIMS;
  float* S0 = stat + 0 * SLAB; float* Q0 = stat + 1 * SLAB;
  float* S1 = stat + 2 * SLAB; float* Q1 = stat + 3 * SLAB;
  float* S2 = stat + 4 * SLAB; float* Q2 = stat + 5 * SLAB;

  const int nb = (n + 1023) / 1024;  // <= 256 required (n <= 262144)
  const float invn = 1.0f / (float)n;
  const int nwaves = GB * 4;

  size_t zf = (size_t)6 * SLAB + n;  // zero stats + wsum
  size_t zmax = (size_t)2 * n > zf ? (size_t)2 * n : zf;
  zero_k<<<dim3((zmax + 255) / 256), dim3(256), 0, stream>>>(deg_i, (size_t)2 * n, stat, zf);
  deg_count_k<<<dim3((e + 255) / 256), dim3(256), 0, stream>>>(dst, deg_i, e);
  dnorm_k<<<dim3((n + 255) / 256), dim3(256), 0, stream>>>(deg_i, dnorm, n);
  cvt_k<<<dim3(2048), dim3(256), 0, stream>>>(nfeat, Xp, dnorm, (size_t)n * 64);
  wsum_k<<<dim3((e + 255) / 256), dim3(256), 0, stream>>>(src, dst, dnorm, wsum, e);
  scan1_k<<<dim3(nb), dim3(256), 0, stream>>>(deg_i, bsum, n);
  scan2_k<<<dim3(1), dim3(256), 0, stream>>>(bsum, nb, row_off, n, e);
  scan3_k<<<dim3(nb), dim3(256), 0, stream>>>(deg_i, bsum, row_off, n);
  build_adj_k<<<dim3((e + 255) / 256), dim3(256), 0, stream>>>(src, dst, row_off, cursor, adj, e);

  // hop 1: Xp -> W1 (stats of h1 -> S0/Q0)
  gather_k<false><<<dim3(GB), dim3(256), 0, stream>>>(
      Xp, W1, row_off, adj, dnorm, wsum, nullptr, nullptr, S0, Q0, n, nwaves);
  affine_k<<<dim3(1), dim3(DIMS), 0, stream>>>(S0, Q0, gamma1, beta1, affA + 0, affB + 0, invn);
  // hop 2: W1 -> Y2 = h2 (stats -> S1/Q1)
  gather_k<true><<<dim3(GB), dim3(256), 0, stream>>>(
      W1, Y2, row_off, adj, dnorm, wsum, affA + 0, affB + 0, S1, Q1, n, nwaves);
  affine_k<<<dim3(1), dim3(DIMS), 0, stream>>>(S1, Q1, gamma1, beta1, affA + DIMS, affB + DIMS, invn);
  // fold stage-1 affine into transposed fp16 weights, then MFMA matmul (stats -> S2/Q2)
  foldw_k<<<dim3(DIMS), dim3(DIMS), 0, stream>>>(conv_w, conv_b, affA + DIMS, affB + DIMS, Wt, cp);
  matmul_k<<<dim3((n + 63) / 64), dim3(256), 0, stream>>>(
      (const uint4*)Y2, (const uint4*)Wt, cp, Zh, S2, Q2, n);
  affine_k<<<dim3(1), dim3(DIMS), 0, stream>>>(S2, Q2, gamma2, beta2, affA + 2 * DIMS, affB + 2 * DIMS, invn);
  // pooling + prediction
  gstart_k<<<dim3((n + 255) / 256), dim3(256), 0, stream>>>(n2g, gstart, n, g);
  pool_pred_k<<<dim3(g), dim3(256), 0, stream>>>((const uint4*)Zh, gstart,
                                                 affA + 2 * DIMS, affB + 2 * DIMS,
                                                 pred_w, pred_b, out);
}

// Round 6
// 410.769 us; speedup vs baseline: 1.2334x; 1.1615x over previous
//
#include <hip/hip_runtime.h>
#include <hip/hip_fp16.h>
#include <cstddef>
#include <cstdint>

constexpr int DIMS = 128;
constexpr float BN_EPS = 1e-5f;
constexpr int NSH = 64;   // stat shadow copies
constexpr int GB = 2048;  // gather grid blocks (x4 waves = 8192 waves)

typedef _Float16 f16x8 __attribute__((ext_vector_type(8)));
typedef float f32x4 __attribute__((ext_vector_type(4)));

static __device__ __forceinline__ f16x8 as_f16x8(uint4 u) {
  union { uint4 u; f16x8 h; } x; x.u = u; return x.h;
}
static __device__ __forceinline__ __half2 as_h2(uint32_t u) {
  union { uint32_t u; __half2 h; } x; x.u = u; return x.h;
}

// ---------------- utility ----------------
__global__ void zero_k(int* __restrict__ ip, size_t ni, float* __restrict__ fp, size_t nf) {
  size_t i = (size_t)blockIdx.x * blockDim.x + threadIdx.x;
  if (i < ni) ip[i] = 0;
  if (i < nf) fp[i] = 0.f;
}

// fp32 -> fp16 conversion with dn pre-scale (dn computed inline from deg):
// Xp[s] = dn[s] * nfeat[s];  also writes dnorm[s]
__global__ void cvt_k(const float* __restrict__ in, uint32_t* __restrict__ out,
                      const int* __restrict__ deg, float* __restrict__ dnorm, size_t n64) {
  size_t i = (size_t)blockIdx.x * blockDim.x + threadIdx.x;
  size_t stride = (size_t)gridDim.x * blockDim.x;
  const float2* in2 = (const float2*)in;
  for (; i < n64; i += stride) {
    size_t row = i >> 6;
    float d = rsqrtf(fmaxf((float)deg[row], 1.0f));
    if ((i & 63) == 0) dnorm[row] = d;
    float2 v = in2[i];
    __half2 h = __floats2half2_rn(v.x * d, v.y * d);
    out[i] = *(const uint32_t*)&h;
  }
}

__global__ void deg_count_k(const int* __restrict__ dst, int* __restrict__ deg, int e) {
  int i = blockIdx.x * blockDim.x + threadIdx.x;
  if (i < e) atomicAdd(&deg[dst[i]], 1);
}

// wsum[n] = sum_{s in in(n)} dn[s]
__global__ void wsum_k(const int* __restrict__ src, const int* __restrict__ dst,
                       const float* __restrict__ dn, float* __restrict__ ws, int e) {
  int i = blockIdx.x * blockDim.x + threadIdx.x;
  if (i < e) atomicAdd(&ws[dst[i]], dn[src[i]]);
}

// ---------------- CSR build: 2-level exclusive scan of degrees ----------------
__global__ void scan1_k(const int* __restrict__ deg, int* __restrict__ bsum, int n) {
  __shared__ int lds[256];
  int t = threadIdx.x;
  int base = blockIdx.x * 1024;
  int s = 0;
  for (int i = t; i < 1024; i += 256) {
    int idx = base + i;
    s += (idx < n) ? deg[idx] : 0;
  }
  lds[t] = s; __syncthreads();
  for (int off = 128; off > 0; off >>= 1) {
    if (t < off) lds[t] += lds[t + off];
    __syncthreads();
  }
  if (t == 0) bsum[blockIdx.x] = lds[0];
}

__global__ void scan2_k(int* __restrict__ bsum, int nb, int* __restrict__ row_off, int n, int e) {
  __shared__ int lds[256];
  int t = threadIdx.x;
  int v = (t < nb) ? bsum[t] : 0;
  lds[t] = v; __syncthreads();
  for (int off = 1; off < 256; off <<= 1) {
    int add = (t >= off) ? lds[t - off] : 0;
    __syncthreads();
    lds[t] += add;
    __syncthreads();
  }
  if (t < nb) bsum[t] = lds[t] - v;  // exclusive base per chunk
  if (t == 0) row_off[n] = e;
}

__global__ void scan3_k(const int* __restrict__ deg, const int* __restrict__ bsum,
                        int* __restrict__ row_off, int n) {
  __shared__ int lds[256];
  int t = threadIdx.x;
  int base = blockIdx.x * 1024 + t * 4;
  int e0 = (base + 0 < n) ? deg[base + 0] : 0;
  int e1 = (base + 1 < n) ? deg[base + 1] : 0;
  int e2 = (base + 2 < n) ? deg[base + 2] : 0;
  int e3 = (base + 3 < n) ? deg[base + 3] : 0;
  int ts = e0 + e1 + e2 + e3;
  lds[t] = ts; __syncthreads();
  for (int off = 1; off < 256; off <<= 1) {
    int add = (t >= off) ? lds[t - off] : 0;
    __syncthreads();
    lds[t] += add;
    __syncthreads();
  }
  int ex = lds[t] - ts + bsum[blockIdx.x];
  if (base + 0 < n) row_off[base + 0] = ex;
  ex += e0;
  if (base + 1 < n) row_off[base + 1] = ex;
  ex += e1;
  if (base + 2 < n) row_off[base + 2] = ex;
  ex += e2;
  if (base + 3 < n) row_off[base + 3] = ex;
}

__global__ void build_adj_k(const int* __restrict__ src, const int* __restrict__ dst,
                            const int* __restrict__ row_off, int* __restrict__ cursor,
                            int* __restrict__ adj, int e) {
  int i = blockIdx.x * blockDim.x + threadIdx.x;
  if (i < e) {
    int dn = dst[i];
    int p = atomicAdd(&cursor[dn], 1);
    adj[row_off[dn] + p] = src[i];
  }
}

// ---------------- propagation hop: grid-stride, TWO nodes per wave in flight -------
// Lane owns 2 features (half2 row element). 8-deep edge pipeline per node stream.
// AFF=false (hop1): acc = sum Xp[s]; v = dn*acc (stats); store W1 = dn*v = dn^2*acc.
// AFF=true  (hop2): acc = sum W1[s]; v = dn*(a*acc + b*wsum[n]) (stats); store v.
template <bool AFF>
__global__ __launch_bounds__(256) void gather_k(
    const uint32_t* __restrict__ Xu, uint32_t* __restrict__ Yout,
    const int* __restrict__ row_off, const int* __restrict__ adj,
    const float* __restrict__ dn, const float* __restrict__ wsum,
    const float* __restrict__ a, const float* __restrict__ b,
    float* __restrict__ sumS, float* __restrict__ sqS, int n, int nwaves) {
  int tid = threadIdx.x;
  int l = tid & 63, w = tid >> 6;
  int wid = blockIdx.x * 4 + w;  // wave-uniform
  uint32_t lu = (uint32_t)l;
  int f0 = 2 * l;
  float af0 = 1.f, bf0 = 0.f, af1 = 1.f, bf1 = 0.f;
  if (AFF) { af0 = a[f0]; bf0 = b[f0]; af1 = a[f0 + 1]; bf1 = b[f0 + 1]; }
  float s0 = 0.f, s1 = 0.f, q0 = 0.f, q1 = 0.f;

  for (int nodeA = wid; nodeA < n; nodeA += 2 * nwaves) {
    const int nodeB = nodeA + nwaves;
    const bool hasB = nodeB < n;
    int ja = row_off[nodeA];
    const int ea = row_off[nodeA + 1];
    int jb = hasB ? row_off[nodeB] : 0;
    const int eb = hasB ? row_off[nodeB + 1] : 0;
    float accA0 = 0.f, accA1 = 0.f, accB0 = 0.f, accB1 = 0.f;

    while ((ja < ea) || (jb < eb)) {
      uint32_t xa[8], xb[8];
      const bool runA = ja < ea, runB = jb < eb;
      if (runA) {  // issue 8 loads for stream A
#pragma unroll
        for (int t = 0; t < 8; ++t) {
          int jj = ja + t;
          int jc = jj < ea ? jj : ea - 1;
          uint32_t sj = (uint32_t)adj[jc];
          uint32_t v = Xu[(sj << 6) + lu];
          xa[t] = (jj < ea) ? v : 0u;
        }
      }
      if (runB) {  // issue 8 more (independent -> 16 in flight)
#pragma unroll
        for (int t = 0; t < 8; ++t) {
          int jj = jb + t;
          int jc = jj < eb ? jj : eb - 1;
          uint32_t sj = (uint32_t)adj[jc];
          uint32_t v = Xu[(sj << 6) + lu];
          xb[t] = (jj < eb) ? v : 0u;
        }
      }
      if (runA) {  // depth-2 fp16 pairwise tree, fp32 accumulate
        __half2 t0 = __hadd2(as_h2(xa[0]), as_h2(xa[1]));
        __half2 t1 = __hadd2(as_h2(xa[2]), as_h2(xa[3]));
        __half2 t2 = __hadd2(as_h2(xa[4]), as_h2(xa[5]));
        __half2 t3 = __hadd2(as_h2(xa[6]), as_h2(xa[7]));
        float2 u0 = __half22float2(__hadd2(t0, t1));
        float2 u1 = __half22float2(__hadd2(t2, t3));
        accA0 += u0.x + u1.x;
        accA1 += u0.y + u1.y;
        ja += 8;
      }
      if (runB) {
        __half2 t0 = __hadd2(as_h2(xb[0]), as_h2(xb[1]));
        __half2 t1 = __hadd2(as_h2(xb[2]), as_h2(xb[3]));
        __half2 t2 = __hadd2(as_h2(xb[4]), as_h2(xb[5]));
        __half2 t3 = __hadd2(as_h2(xb[6]), as_h2(xb[7]));
        float2 u0 = __half22float2(__hadd2(t0, t1));
        float2 u1 = __half22float2(__hadd2(t2, t3));
        accB0 += u0.x + u1.x;
        accB1 += u0.y + u1.y;
        jb += 8;
      }
    }

    {  // finalize node A
      float dnn = dn[nodeA];
      float v0, v1;
      if constexpr (AFF) {
        float wsn = wsum[nodeA];
        v0 = dnn * fmaf(af0, accA0, bf0 * wsn);
        v1 = dnn * fmaf(af1, accA1, bf1 * wsn);
        __half2 hv = __floats2half2_rn(v0, v1);
        Yout[((uint32_t)nodeA << 6) + lu] = *(const uint32_t*)&hv;
      } else {
        v0 = dnn * accA0;
        v1 = dnn * accA1;
        __half2 hv = __floats2half2_rn(v0 * dnn, v1 * dnn);  // W1 = dn^2*acc
        Yout[((uint32_t)nodeA << 6) + lu] = *(const uint32_t*)&hv;
      }
      s0 += v0; s1 += v1; q0 += v0 * v0; q1 += v1 * v1;
    }
    if (hasB) {  // finalize node B
      float dnn = dn[nodeB];
      float v0, v1;
      if constexpr (AFF) {
        float wsn = wsum[nodeB];
        v0 = dnn * fmaf(af0, accB0, bf0 * wsn);
        v1 = dnn * fmaf(af1, accB1, bf1 * wsn);
        __half2 hv = __floats2half2_rn(v0, v1);
        Yout[((uint32_t)nodeB << 6) + lu] = *(const uint32_t*)&hv;
      } else {
        v0 = dnn * accB0;
        v1 = dnn * accB1;
        __half2 hv = __floats2half2_rn(v0 * dnn, v1 * dnn);
        Yout[((uint32_t)nodeB << 6) + lu] = *(const uint32_t*)&hv;
      }
      s0 += v0; s1 += v1; q0 += v0 * v0; q1 += v1 * v1;
    }
  }

  // block epilogue: LDS cross-wave reduce, then 256 lane-atomics per block
  __shared__ float red[4][256];
  red[w][l] = s0; red[w][64 + l] = s1; red[w][128 + l] = q0; red[w][192 + l] = q1;
  __syncthreads();
  float t = red[0][tid] + red[1][tid] + red[2][tid] + red[3][tid];
  int comp = tid >> 6, li = tid & 63;
  int sh = blockIdx.x & (NSH - 1);
  float* dstp = ((comp & 2) ? sqS : sumS) + sh * DIMS;
  atomicAdd(&dstp[2 * li + (comp & 1)], t);
}

// ---------------- BN affine coefficients (reduces NSH shadow copies) ----------------
__global__ void affine_k(const float* __restrict__ sum, const float* __restrict__ sq,
                         const float* __restrict__ gamma, const float* __restrict__ beta,
                         float* __restrict__ a, float* __restrict__ b, float invn) {
  int d = threadIdx.x;
  float s = 0.f, q = 0.f;
  for (int k = 0; k < NSH; ++k) { s += sum[k * DIMS + d]; q += sq[k * DIMS + d]; }
  float mu = s * invn;
  float var = q * invn - mu * mu;
  float rs = rsqrtf(var + BN_EPS);
  float ad = rs * gamma[d];
  a[d] = ad;
  b[d] = beta[d] - mu * ad;
}

// fold pre-matmul affine into weights, TRANSPOSED fp16:
// Wt[o][d] = (half)(a2[d]*W[d][o]);  cp[o] = sum_d b2[d]*W[d][o] + cb[o]
__global__ void foldw_k(const float* __restrict__ W, const float* __restrict__ cb,
                        const float* __restrict__ a2, const float* __restrict__ b2,
                        __half* __restrict__ Wt, float* __restrict__ cp) {
  int o = blockIdx.x;
  int d = threadIdx.x;
  float w = W[d * DIMS + o];
  Wt[o * DIMS + d] = __float2half(a2[d] * w);
  __shared__ float red[128];
  red[d] = b2[d] * w;
  __syncthreads();
  for (int off = 64; off > 0; off >>= 1) {
    if (d < off) red[d] += red[d + off];
    __syncthreads();
  }
  if (d == 0) cp[o] = red[0] + cb[o];
}

// ---------------- Z = X @ W + cp via MFMA (fp16 in/out, f32 accum, fused BN stats) ----
__global__ __launch_bounds__(256) void matmul_k(
    const uint4* __restrict__ X, const uint4* __restrict__ Wt,
    const float* __restrict__ cp, __half* __restrict__ Z,
    float* __restrict__ sumS, float* __restrict__ sqS, int n) {
  int tid = threadIdx.x;
  int l = tid & 63, w = tid >> 6;
  int rowg = l & 15;  // A-row / B-col / D-col within tile
  int kg = l >> 4;    // k-group
  int r0 = (blockIdx.x * 4 + w) * 16;
  bool active = r0 < n;

  __shared__ float sred[4][128], qred[4][128];
  float svals[8], qvals[8];

  if (active) {
    f32x4 acc[8] = {};
    const uint4* xrow = X + (size_t)(r0 + rowg) * 16;
    bool arow_ok = (r0 + rowg) < n;
#pragma unroll
    for (int kk = 0; kk < 4; ++kk) {
      uint4 au = arow_ok ? xrow[kk * 4 + kg] : make_uint4(0u, 0u, 0u, 0u);
      f16x8 afr = as_f16x8(au);
#pragma unroll
      for (int c = 0; c < 8; ++c) {
        f16x8 bfr = as_f16x8(Wt[(size_t)(c * 16 + rowg) * 16 + kk * 4 + kg]);
        acc[c] = __builtin_amdgcn_mfma_f32_16x16x32_f16(afr, bfr, acc[c], 0, 0, 0);
      }
    }
#pragma unroll
    for (int c = 0; c < 8; ++c) {
      float cpv = cp[c * 16 + rowg];
      float s = 0.f, q = 0.f;
#pragma unroll
      for (int r = 0; r < 4; ++r) {
        int row = r0 + kg * 4 + r;
        float vv = acc[c][r] + cpv;
        bool ok = row < n;
        vv = ok ? vv : 0.f;
        s += vv; q += vv * vv;
        if (ok) Z[(size_t)row * DIMS + c * 16 + rowg] = __float2half(vv);
      }
      s += __shfl_xor(s, 16); s += __shfl_xor(s, 32);
      q += __shfl_xor(q, 16); q += __shfl_xor(q, 32);
      svals[c] = s; qvals[c] = q;
    }
  }
  if (active) {
    if (kg == 0) {
#pragma unroll
      for (int c = 0; c < 8; ++c) {
        sred[w][c * 16 + rowg] = svals[c];
        qred[w][c * 16 + rowg] = qvals[c];
      }
    }
  } else {
    sred[w][l] = 0.f; sred[w][64 + l] = 0.f;
    qred[w][l] = 0.f; qred[w][64 + l] = 0.f;
  }
  __syncthreads();
  int f = tid & 127;
  int sh = blockIdx.x & (NSH - 1);
  if (tid < 128) {
    float s = sred[0][f] + sred[1][f] + sred[2][f] + sred[3][f];
    atomicAdd(&sumS[sh * DIMS + f], s);
  } else {
    float q = qred[0][f] + qred[1][f] + qred[2][f] + qred[3][f];
    atomicAdd(&sqS[sh * DIMS + f], q);
  }
}

// ---------------- graph segment starts (node2graph is sorted) ----------------
__global__ void gstart_k(const int* __restrict__ n2g, int* __restrict__ gstart, int n, int G) {
  int i = blockIdx.x * blockDim.x + threadIdx.x;
  if (i >= n) return;
  int g = n2g[i];
  int gp = (i == 0) ? -1 : n2g[i - 1];
  for (int x = gp + 1; x <= g; ++x) gstart[x] = i;
  if (i == n - 1) {
    for (int x = g + 1; x <= G; ++x) gstart[x] = n;
  }
}

// ---------------- BN2-apply + relu + mean-pool + 128->2 projection ----------------
__global__ __launch_bounds__(512) void pool_pred_k(
    const uint4* __restrict__ Z, const int* __restrict__ gstart,
    const float* __restrict__ a3, const float* __restrict__ b3,
    const float* __restrict__ pw, const float* __restrict__ pb,
    float* __restrict__ out) {
  int g = blockIdx.x;
  int tid = threadIdx.x;
  int l = tid & 63, w = tid >> 6;  // w 0..7
  int grp = l >> 4, fl = l & 15;
  int f0 = fl * 8;
  float av[8], bv[8];
#pragma unroll
  for (int q = 0; q < 8; ++q) { av[q] = a3[f0 + q]; bv[q] = b3[f0 + q]; }
  int s = gstart[g], e = gstart[g + 1];
  float rs[8] = {0.f, 0.f, 0.f, 0.f, 0.f, 0.f, 0.f, 0.f};
  for (int ni = s + (w * 4 + grp); ni < e; ni += 32) {
    uint4 zv = Z[(size_t)ni * 16 + fl];
    const __half2* h = (const __half2*)&zv;
#pragma unroll
    for (int q = 0; q < 4; ++q) {
      float2 z = __half22float2(h[q]);
      rs[2 * q] += fmaxf(fmaf(z.x, av[2 * q], bv[2 * q]), 0.f);
      rs[2 * q + 1] += fmaxf(fmaf(z.y, av[2 * q + 1], bv[2 * q + 1]), 0.f);
    }
  }
  float p0 = 0.f, p1 = 0.f;
#pragma unroll
  for (int q = 0; q < 8; ++q) {
    p0 += rs[q] * pw[(f0 + q) * 2 + 0];
    p1 += rs[q] * pw[(f0 + q) * 2 + 1];
  }
  __shared__ float r[2][512];
  r[0][tid] = p0; r[1][tid] = p1;
  __syncthreads();
  for (int off = 256; off > 0; off >>= 1) {
    if (tid < off) { r[0][tid] += r[0][tid + off]; r[1][tid] += r[1][tid + off]; }
    __syncthreads();
  }
  if (tid == 0) {
    float inv = 1.f / fmaxf((float)(e - s), 1.f);
    out[g * 2 + 0] = r[0][0] * inv + pb[0];
    out[g * 2 + 1] = r[1][0] * inv + pb[1];
  }
}

// ---------------- host launch ----------------
extern "C" void kernel_launch(void* const* d_in, const int* in_sizes, int n_in,
                              void* d_out, int out_size, void* d_ws, size_t ws_size,
                              hipStream_t stream) {
  const float* nfeat  = (const float*)d_in[0];
  const int*   src    = (const int*)d_in[1];
  const int*   dst    = (const int*)d_in[2];
  const int*   n2g    = (const int*)d_in[3];
  // d_in[4] = num_graphs (device scalar) — derived from out_size instead
  const float* conv_w = (const float*)d_in[5];
  const float* conv_b = (const float*)d_in[6];
  const float* gamma1 = (const float*)d_in[7];
  const float* beta1  = (const float*)d_in[8];
  const float* gamma2 = (const float*)d_in[9];
  const float* beta2  = (const float*)d_in[10];
  const float* pred_w = (const float*)d_in[11];
  const float* pred_b = (const float*)d_in[12];
  float* out = (float*)d_out;
  (void)n_in; (void)ws_size;

  const int n = in_sizes[0] / DIMS;
  const int e = in_sizes[1];
  const int g = out_size / 2;

  char* p = (char*)d_ws;
  auto alloc = [&](size_t bytes) { char* r = p; p += (bytes + 255) & ~(size_t)255; return r; };
  uint32_t* Xp  = (uint32_t*)alloc((size_t)n * 64 * 4);  // dn-scaled input rows (fp16)
  uint32_t* W1  = (uint32_t*)alloc((size_t)n * 64 * 4);  // dn^2-scaled h1 rows (fp16)
  uint32_t* Y2  = (uint32_t*)alloc((size_t)n * 64 * 4);  // h2 rows (fp16)
  __half*   Zh  = (__half*)alloc((size_t)n * 64 * 4);    // matmul output rows (fp16)
  float* dnorm = (float*)alloc((size_t)n * 4);
  float* stat  = (float*)alloc(((size_t)6 * NSH * DIMS + n) * 4);  // stats + wsum
  float* wsum  = stat + 6 * NSH * DIMS;
  float* affA  = (float*)alloc(3 * DIMS * 4);
  float* affB  = (float*)alloc(3 * DIMS * 4);
  __half* Wt   = (__half*)alloc(DIMS * DIMS * 2);
  float* cp    = (float*)alloc(DIMS * 4);
  int* deg_i   = (int*)alloc((size_t)n * 2 * 4);  // deg + cursor
  int* cursor  = deg_i + n;
  int* row_off = (int*)alloc(((size_t)n + 1) * 4);
  int* adj     = (int*)alloc((size_t)e * 4);
  int* bsum    = (int*)alloc(2048 * 4);
  int* gstart  = (int*)alloc(((size_t)g + 1) * 4);

  const int SLAB = NSH * DIMS;
  float* S0 = stat + 0 * SLAB; float* Q0 = stat + 1 * SLAB;
  float* S1 = stat + 2 * SLAB; float* Q1 = stat + 3 * SLAB;
  float* S2 = stat + 4 * SLAB; float* Q2 = stat + 5 * SLAB;

  const int nb = (n + 1023) / 1024;  // <= 256 required (n <= 262144)
  const float invn = 1.0f / (float)n;
  const int nwaves = GB * 4;

  size_t zf = (size_t)6 * SLAB + n;  // zero stats + wsum
  size_t zmax = (size_t)2 * n > zf ? (size_t)2 * n : zf;
  zero_k<<<dim3((zmax + 255) / 256), dim3(256), 0, stream>>>(deg_i, (size_t)2 * n, stat, zf);
  deg_count_k<<<dim3((e + 255) / 256), dim3(256), 0, stream>>>(dst, deg_i, e);
  cvt_k<<<dim3(2048), dim3(256), 0, stream>>>(nfeat, Xp, deg_i, dnorm, (size_t)n * 64);
  wsum_k<<<dim3((e + 255) / 256), dim3(256), 0, stream>>>(src, dst, dnorm, wsum, e);
  scan1_k<<<dim3(nb), dim3(256), 0, stream>>>(deg_i, bsum, n);
  scan2_k<<<dim3(1), dim3(256), 0, stream>>>(bsum, nb, row_off, n, e);
  scan3_k<<<dim3(nb), dim3(256), 0, stream>>>(deg_i, bsum, row_off, n);
  build_adj_k<<<dim3((e + 255) / 256), dim3(256), 0, stream>>>(src, dst, row_off, cursor, adj, e);

  // hop 1: Xp -> W1 (stats of h1 -> S0/Q0)
  gather_k<false><<<dim3(GB), dim3(256), 0, stream>>>(
      Xp, W1, row_off, adj, dnorm, wsum, nullptr, nullptr, S0, Q0, n, nwaves);
  affine_k<<<dim3(1), dim3(DIMS), 0, stream>>>(S0, Q0, gamma1, beta1, affA + 0, affB + 0, invn);
  // hop 2: W1 -> Y2 = h2 (stats -> S1/Q1)
  gather_k<true><<<dim3(GB), dim3(256), 0, stream>>>(
      W1, Y2, row_off, adj, dnorm, wsum, affA + 0, affB + 0, S1, Q1, n, nwaves);
  affine_k<<<dim3(1), dim3(DIMS), 0, stream>>>(S1, Q1, gamma1, beta1, affA + DIMS, affB + DIMS, invn);
  // fold stage-1 affine into transposed fp16 weights, then MFMA matmul (stats -> S2/Q2)
  foldw_k<<<dim3(DIMS), dim3(DIMS), 0, stream>>>(conv_w, conv_b, affA + DIMS, affB + DIMS, Wt, cp);
  matmul_k<<<dim3((n + 63) / 64), dim3(256), 0, stream>>>(
      (const uint4*)Y2, (const uint4*)Wt, cp, Zh, S2, Q2, n);
  affine_k<<<dim3(1), dim3(DIMS), 0, stream>>>(S2, Q2, gamma2, beta2, affA + 2 * DIMS, affB + 2 * DIMS, invn);
  // pooling + prediction
  gstart_k<<<dim3((n + 255) / 256), dim3(256), 0, stream>>>(n2g, gstart, n, g);
  pool_pred_k<<<dim3(g), dim3(512), 0, stream>>>((const uint4*)Zh, gstart,
                                                 affA + 2 * DIMS, affB + 2 * DIMS,
                                                 pred_w, pred_b, out);
}